// Round 2
// baseline (220.427 us; speedup 1.0000x reference)
//
#include <hip/hip_runtime.h>
#include <math.h>

#define N_NODES   50000
#define EMBED_DIM 320
#define N_EDGES   400000
#define HID       64

// ---------------------------------------------------------------------------
// Kernel 1: cterm[j] = b1[j] + sum_k embed[nid][k] * W1[(640+k)*64 + j]
// (the "center" third of the MLP's first layer -- constant across all edges)
// ---------------------------------------------------------------------------
__global__ void prep_kernel(const float* __restrict__ embed,
                            const int* __restrict__ node_id,
                            const float* __restrict__ W1,
                            const float* __restrict__ b1,
                            float* __restrict__ cterm) {
    int j = threadIdx.x;            // 0..63
    int nid = node_id[0];
    const float* erow = embed + (size_t)nid * EMBED_DIM;
    float s = b1[j];
    #pragma unroll 8
    for (int k = 0; k < EMBED_DIM; ++k)
        s = fmaf(erow[k], W1[(size_t)(2 * EMBED_DIM + k) * HID + j], s);
    cterm[j] = s;
}

// ---------------------------------------------------------------------------
// Kernel 2: P[n][0:64]  = embed[n] @ W1[0:320]      (col-term)
//           P[n][64:128]= embed[n] @ W1[320:640]    (row-term)
// i.e. one fp32 GEMM: [50000 x 320] @ [320 x 128] -> [50000 x 128]
// BM=128, BN=128(full), BK=32; 256 threads; 8x8 register tile per thread.
// ---------------------------------------------------------------------------
#define BM 128
#define BK 32
#define ESTRIDE (BM + 4)    // 132: keeps float4 alignment (132 % 4 == 0)
#define WSTRIDE (128 + 4)

__global__ __launch_bounds__(256) void node_gemm(const float* __restrict__ E,
                                                 const float* __restrict__ W1,
                                                 float* __restrict__ P) {
    __shared__ float Es[BK][ESTRIDE];   // transposed: Es[k][m]
    __shared__ float Ws[BK][WSTRIDE];   // Ws[k][n]

    const int tid = threadIdx.x;
    const int m0  = blockIdx.x * BM;
    const int tx  = tid & 15;           // 16 col-groups * 8 cols
    const int ty  = tid >> 4;           // 16 row-groups * 8 rows

    float acc[8][8] = {};

    for (int kt = 0; kt < EMBED_DIM; kt += BK) {
        // ---- stage E tile (128 rows x 32 k), store transposed ----
        #pragma unroll
        for (int p = 0; p < 4; ++p) {
            int idx = tid + p * 256;        // 0..1023 float4 slots
            int r   = idx >> 3;             // 0..127
            int c4  = (idx & 7) * 4;        // 0..28
            int gr  = m0 + r;
            float4 v = make_float4(0.f, 0.f, 0.f, 0.f);
            if (gr < N_NODES)
                v = *(const float4*)(E + (size_t)gr * EMBED_DIM + kt + c4);
            Es[c4 + 0][r] = v.x;
            Es[c4 + 1][r] = v.y;
            Es[c4 + 2][r] = v.z;
            Es[c4 + 3][r] = v.w;
        }
        // ---- stage W tile (32 k x 128 n) from the two W1 column-blocks ----
        #pragma unroll
        for (int p = 0; p < 4; ++p) {
            int idx = tid + p * 256;
            int r   = idx >> 5;             // 0..31 (k within tile)
            int c4  = (idx & 31) * 4;       // 0..124
            int k   = kt + r;
            const float* src = (c4 < 64)
                ? (W1 + (size_t)k * HID + c4)
                : (W1 + (size_t)(EMBED_DIM + k) * HID + (c4 - 64));
            *(float4*)&Ws[r][c4] = *(const float4*)src;
        }
        __syncthreads();

        // ---- compute ----
        #pragma unroll
        for (int kk = 0; kk < BK; ++kk) {
            float a[8], b[8];
            *(float4*)&a[0] = *(const float4*)&Es[kk][ty * 8];
            *(float4*)&a[4] = *(const float4*)&Es[kk][ty * 8 + 4];
            *(float4*)&b[0] = *(const float4*)&Ws[kk][tx * 8];
            *(float4*)&b[4] = *(const float4*)&Ws[kk][tx * 8 + 4];
            #pragma unroll
            for (int i = 0; i < 8; ++i)
                #pragma unroll
                for (int j = 0; j < 8; ++j)
                    acc[i][j] = fmaf(a[i], b[j], acc[i][j]);
        }
        __syncthreads();
    }

    // ---- store ----
    #pragma unroll
    for (int i = 0; i < 8; ++i) {
        int gr = m0 + ty * 8 + i;
        if (gr < N_NODES) {
            float* dst = P + (size_t)gr * 128 + tx * 8;
            *(float4*)(dst + 0) = *(float4*)&acc[i][0];
            *(float4*)(dst + 4) = *(float4*)&acc[i][4];
        }
    }
}

// ---------------------------------------------------------------------------
// Kernel 3: per-edge. 16 lanes per edge, float4 per lane.
// h = relu(P[col][0:64] + P[row][64:128] + cterm); w = h.W2 + b2
// gate = (log(e) - log1p(-e) + w)/tmp ; out = sigmoid(gate)
// NOTE: edge_index arrives as int32 (harness converts integer inputs).
// ---------------------------------------------------------------------------
__global__ __launch_bounds__(256) void edge_kernel(const int* __restrict__ eidx,
                                                   const float* __restrict__ eps,
                                                   const float* __restrict__ P,
                                                   const float* __restrict__ cterm,
                                                   const float* __restrict__ W2,
                                                   const float* __restrict__ b2,
                                                   const float* __restrict__ tmp,
                                                   float* __restrict__ out) {
    const int gid = blockIdx.x * blockDim.x + threadIdx.x;
    const int e   = gid >> 4;          // edge id
    const int q   = gid & 15;          // lane within edge group
    if (e >= N_EDGES) return;

    // defensive clamp: a bad index becomes a wrong value (absmax diagnostic),
    // not a device fault that kills the whole bench run.
    int col = eidx[e];
    int row = eidx[N_EDGES + e];
    col = min(max(col, 0), N_NODES - 1);
    row = min(max(row, 0), N_NODES - 1);

    float4 a  = *(const float4*)(P + (size_t)col * 128 + q * 4);
    float4 b  = *(const float4*)(P + (size_t)row * 128 + 64 + q * 4);
    float4 c  = *(const float4*)(cterm + q * 4);
    float4 w2 = *(const float4*)(W2 + q * 4);

    float h0 = fmaxf(a.x + b.x + c.x, 0.f);
    float h1 = fmaxf(a.y + b.y + c.y, 0.f);
    float h2 = fmaxf(a.z + b.z + c.z, 0.f);
    float h3 = fmaxf(a.w + b.w + c.w, 0.f);
    float s = h0 * w2.x + h1 * w2.y + h2 * w2.z + h3 * w2.w;

    // reduce across the 16 lanes of this edge (xor masks stay in-group)
    s += __shfl_xor(s, 1);
    s += __shfl_xor(s, 2);
    s += __shfl_xor(s, 4);
    s += __shfl_xor(s, 8);

    if (q == 0) {
        float w  = s + b2[0];
        const float bias = 0.0001f;               // SAMPLE_BIAS + 1e-4
        float ee = eps[e] * (1.0f - 2.0f * bias) + bias;
        float gate = (logf(ee) - log1pf(-ee) + w) / tmp[0];
        out[e] = 1.0f / (1.0f + expf(-gate));
    }
}

// ---------------------------------------------------------------------------
extern "C" void kernel_launch(void* const* d_in, const int* in_sizes, int n_in,
                              void* d_out, int out_size, void* d_ws, size_t ws_size,
                              hipStream_t stream) {
    // inputs (setup_inputs order): x, embed, edge_index, node_id, tmp, eps,
    //                              W1, b1, W2, b2
    const float* embed = (const float*)d_in[1];
    const int*   eidx  = (const int*)d_in[2];     // int32 per harness contract
    const int*   nid   = (const int*)d_in[3];
    const float* tmp   = (const float*)d_in[4];
    const float* eps   = (const float*)d_in[5];
    const float* W1    = (const float*)d_in[6];
    const float* b1    = (const float*)d_in[7];
    const float* W2    = (const float*)d_in[8];
    const float* b2    = (const float*)d_in[9];
    float*       out   = (float*)d_out;

    // workspace layout: P[50000*128] floats, then cterm[64]
    float* P     = (float*)d_ws;
    float* cterm = P + (size_t)N_NODES * 128;

    prep_kernel<<<1, 64, 0, stream>>>(embed, nid, W1, b1, cterm);

    int gemm_blocks = (N_NODES + BM - 1) / BM;   // 391
    node_gemm<<<gemm_blocks, 256, 0, stream>>>(embed, W1, P);

    int edge_threads = N_EDGES * 16;
    edge_kernel<<<(edge_threads + 255) / 256, 256, 0, stream>>>(
        eidx, eps, P, cterm, W2, b2, tmp, out);
}

// Round 3
// 198.637 us; speedup vs baseline: 1.1097x; 1.1097x over previous
//
#include <hip/hip_runtime.h>
#include <math.h>

#define N_NODES   50000
#define EMBED_DIM 320
#define N_EDGES   400000
#define HID       64

// ---------------------------------------------------------------------------
// node_gemm: P[n][0:64]   = embed[n] @ W1[0:320]   + cterm   (col-term)
//            P[n][64:128] = embed[n] @ W1[320:640]           (row-term)
// where cterm = b1 + embed[nid] @ W1[640:960]  (computed redundantly per block;
// 80 FMA/thread — removes the separate prep kernel + its serial launch).
// BM=64 (782 blocks -> ~3 blk/CU, fixes the 13.5% occupancy of BM=128),
// BK=32, 256 threads, 4x8 acc/thread.
// Bank-conflict design:
//   Es (A-tile, transposed [k][m]): XOR-swizzled store col = m ^ ((k>>2&7)<<2)
//     -> scalar transpose-writes go 4-way -> ~2-way (free); reads stay b128.
//   Ws reads at cols tx*4 / 64+tx*4 -> 2-way (free) instead of 4-way at tx*8.
// ---------------------------------------------------------------------------
#define BM 64
#define BK 32
#define ES_STRIDE 68     // 64 + 4, float4-aligned
#define WS_STRIDE 132    // 128 + 4

__global__ __launch_bounds__(256) void node_gemm(const float* __restrict__ E,
                                                 const float* __restrict__ W1,
                                                 const float* __restrict__ b1,
                                                 const int* __restrict__ node_id,
                                                 float* __restrict__ P) {
    __shared__ float Es[BK][ES_STRIDE];
    __shared__ float Ws[BK][WS_STRIDE];
    __shared__ float red[4][64];
    __shared__ float cterm[64];

    const int tid = threadIdx.x;
    const int m0  = blockIdx.x * BM;
    const int tx  = tid & 15;        // 16 col-groups (4 cols each, x2 halves)
    const int ty  = tid >> 4;        // 16 row-groups (4 rows each)

    // ---- per-block cterm: b1 + embed[nid] @ W1[640:960] ----
    {
        const int j = tid & 63;      // output col
        const int g = tid >> 6;      // k-quarter
        const int nid = node_id[0];
        const float* erow = E + (size_t)nid * EMBED_DIM;
        float s = 0.f;
        #pragma unroll 4
        for (int k = g * 80; k < (g + 1) * 80; ++k)
            s = fmaf(erow[k], W1[(size_t)(2 * EMBED_DIM + k) * HID + j], s);
        red[g][j] = s;
    }
    __syncthreads();
    if (tid < 64)
        cterm[tid] = b1[tid] + red[0][tid] + red[1][tid] + red[2][tid] + red[3][tid];
    // (loop syncs below order cterm[] before the epilogue reads it)

    float acc[4][8] = {};

    for (int kt = 0; kt < EMBED_DIM; kt += BK) {
        // ---- stage Es: 64 rows x 32 k, transposed, XOR-swizzled ----
        #pragma unroll
        for (int p = 0; p < 2; ++p) {
            int idx = tid + p * 256;       // 0..511 float4 slots
            int r   = idx >> 3;            // row m, 0..63
            int c4  = (idx & 7) * 4;       // k-offset, 0..28
            int gr  = m0 + r;
            float4 v = make_float4(0.f, 0.f, 0.f, 0.f);
            if (gr < N_NODES)
                v = *(const float4*)(E + (size_t)gr * EMBED_DIM + kt + c4);
            int sc = r ^ (((c4 >> 2) & 7) << 2);   // swizzled column
            Es[c4 + 0][sc] = v.x;
            Es[c4 + 1][sc] = v.y;
            Es[c4 + 2][sc] = v.z;
            Es[c4 + 3][sc] = v.w;
        }
        // ---- stage Ws: 32 k x 128 n from the two W1 column-blocks ----
        #pragma unroll
        for (int p = 0; p < 4; ++p) {
            int idx = tid + p * 256;       // 0..1023
            int r   = idx >> 5;            // k, 0..31
            int c4  = (idx & 31) * 4;      // n, 0..124
            int k   = kt + r;
            const float* src = (c4 < 64)
                ? (W1 + (size_t)k * HID + c4)
                : (W1 + (size_t)(EMBED_DIM + k) * HID + (c4 - 64));
            *(float4*)&Ws[r][c4] = *(const float4*)src;
        }
        __syncthreads();

        // ---- compute: 32 FMA/thread per kk ----
        #pragma unroll
        for (int kk = 0; kk < BK; ++kk) {
            float4 av  = *(const float4*)&Es[kk][(ty * 4) ^ (((kk >> 2) & 7) << 2)];
            float4 bv0 = *(const float4*)&Ws[kk][tx * 4];
            float4 bv1 = *(const float4*)&Ws[kk][64 + tx * 4];
            float a[4] = {av.x, av.y, av.z, av.w};
            float b[8] = {bv0.x, bv0.y, bv0.z, bv0.w, bv1.x, bv1.y, bv1.z, bv1.w};
            #pragma unroll
            for (int i = 0; i < 4; ++i)
                #pragma unroll
                for (int j = 0; j < 8; ++j)
                    acc[i][j] = fmaf(a[i], b[j], acc[i][j]);
        }
        __syncthreads();
    }

    // ---- epilogue: add cterm to the col-half, store ----
    #pragma unroll
    for (int i = 0; i < 4; ++i) {
        int gr = m0 + ty * 4 + i;
        if (gr < N_NODES) {
            float4 o0, o1;
            o0.x = acc[i][0] + cterm[tx * 4 + 0];
            o0.y = acc[i][1] + cterm[tx * 4 + 1];
            o0.z = acc[i][2] + cterm[tx * 4 + 2];
            o0.w = acc[i][3] + cterm[tx * 4 + 3];
            o1.x = acc[i][4];
            o1.y = acc[i][5];
            o1.z = acc[i][6];
            o1.w = acc[i][7];
            float* dst = P + (size_t)gr * 128;
            *(float4*)(dst + tx * 4)      = o0;
            *(float4*)(dst + 64 + tx * 4) = o1;
        }
    }
}

// ---------------------------------------------------------------------------
// edge_kernel: 8 lanes/edge, 2x float4 per operand per lane (256B/row-half).
// h = relu(P[col][0:64] + P[row][64:128]); w = h.W2 + b2   (cterm is in P)
// gate = (log(e) - log1p(-e) + w)/tmp ; out = sigmoid(gate)
// ---------------------------------------------------------------------------
__global__ __launch_bounds__(256) void edge_kernel(const int* __restrict__ eidx,
                                                   const float* __restrict__ eps,
                                                   const float* __restrict__ P,
                                                   const float* __restrict__ W2,
                                                   const float* __restrict__ b2,
                                                   const float* __restrict__ tmp,
                                                   float* __restrict__ out) {
    const int gid = blockIdx.x * blockDim.x + threadIdx.x;
    const int e   = gid >> 3;          // edge id
    const int q   = gid & 7;           // lane within edge group
    if (e >= N_EDGES) return;

    // defensive clamp: bad index -> wrong value (absmax diagnostic), not a fault
    int col = eidx[e];
    int row = eidx[N_EDGES + e];
    col = min(max(col, 0), N_NODES - 1);
    row = min(max(row, 0), N_NODES - 1);

    const float* pc = P + (size_t)col * 128 + q * 8;
    const float* pr = P + (size_t)row * 128 + 64 + q * 8;
    float4 a0 = *(const float4*)(pc + 0);
    float4 a1 = *(const float4*)(pc + 4);
    float4 c0 = *(const float4*)(pr + 0);
    float4 c1 = *(const float4*)(pr + 4);
    float4 w0 = *(const float4*)(W2 + q * 8);
    float4 w1 = *(const float4*)(W2 + q * 8 + 4);

    float s = 0.f;
    s = fmaf(fmaxf(a0.x + c0.x, 0.f), w0.x, s);
    s = fmaf(fmaxf(a0.y + c0.y, 0.f), w0.y, s);
    s = fmaf(fmaxf(a0.z + c0.z, 0.f), w0.z, s);
    s = fmaf(fmaxf(a0.w + c0.w, 0.f), w0.w, s);
    s = fmaf(fmaxf(a1.x + c1.x, 0.f), w1.x, s);
    s = fmaf(fmaxf(a1.y + c1.y, 0.f), w1.y, s);
    s = fmaf(fmaxf(a1.z + c1.z, 0.f), w1.z, s);
    s = fmaf(fmaxf(a1.w + c1.w, 0.f), w1.w, s);

    // reduce across the 8 lanes of this edge (xor masks stay in-group)
    s += __shfl_xor(s, 1);
    s += __shfl_xor(s, 2);
    s += __shfl_xor(s, 4);

    if (q == 0) {
        float w  = s + b2[0];
        const float bias = 0.0001f;               // SAMPLE_BIAS + 1e-4
        float ee = eps[e] * (1.0f - 2.0f * bias) + bias;
        float gate = (logf(ee) - log1pf(-ee) + w) / tmp[0];
        out[e] = 1.0f / (1.0f + expf(-gate));
    }
}

// ---------------------------------------------------------------------------
extern "C" void kernel_launch(void* const* d_in, const int* in_sizes, int n_in,
                              void* d_out, int out_size, void* d_ws, size_t ws_size,
                              hipStream_t stream) {
    // inputs (setup_inputs order): x, embed, edge_index, node_id, tmp, eps,
    //                              W1, b1, W2, b2
    const float* embed = (const float*)d_in[1];
    const int*   eidx  = (const int*)d_in[2];     // int32 per harness contract
    const int*   nid   = (const int*)d_in[3];
    const float* tmp   = (const float*)d_in[4];
    const float* eps   = (const float*)d_in[5];
    const float* W1    = (const float*)d_in[6];
    const float* b1    = (const float*)d_in[7];
    const float* W2    = (const float*)d_in[8];
    const float* b2    = (const float*)d_in[9];
    float*       out   = (float*)d_out;

    float* P = (float*)d_ws;   // [50000][128]

    int gemm_blocks = (N_NODES + BM - 1) / BM;    // 782
    node_gemm<<<gemm_blocks, 256, 0, stream>>>(embed, W1, b1, nid, P);

    int edge_threads = N_EDGES * 8;               // 3.2M
    edge_kernel<<<(edge_threads + 255) / 256, 256, 0, stream>>>(
        eidx, eps, P, W2, b2, tmp, out);
}

// Round 5
// 173.475 us; speedup vs baseline: 1.2707x; 1.1450x over previous
//
#include <hip/hip_runtime.h>
#include <math.h>

#define N_NODES   50000
#define EMBED_DIM 320
#define N_EDGES   400000
#define HID       64

typedef __bf16 bf16x8 __attribute__((ext_vector_type(8)));
typedef float  f32x4  __attribute__((ext_vector_type(4)));

// ---------------------------------------------------------------------------
// prep_b: repack W1's two 320x64 column-blocks into MFMA B-fragment order (bf16).
//   B[k][c] = W1[k + (c>=64)*320][c&63],  k=0..319, c=0..127
//   Bg[((s*8+f)*64 + l)*8 + j] = (bf16) B[32s + 8*(l>>4) + j][16f + (l&15)]
// so the GEMM wave's B-frag load is one coalesced dwordx4 per (s,f), L2-hit.
// ---------------------------------------------------------------------------
__global__ __launch_bounds__(256) void prep_b(const float* __restrict__ W1,
                                              __bf16* __restrict__ Bg) {
    int chunk = blockIdx.x * 256 + threadIdx.x;   // 5120 = 10 steps * 8 frags * 64 lanes
    if (chunk >= 5120) return;
    int l  = chunk & 63;
    int sf = chunk >> 6;
    int f  = sf & 7, s = sf >> 3;
    int c  = f * 16 + (l & 15);
    int k0 = s * 32 + (l >> 4) * 8;
    const float* src = W1 + ((size_t)k0 + (c >= 64 ? EMBED_DIM : 0)) * HID + (c & 63);
    __bf16* dst = Bg + (size_t)chunk * 8;
    #pragma unroll
    for (int j = 0; j < 8; ++j) dst[j] = (__bf16)src[(size_t)j * HID];
}

// ---------------------------------------------------------------------------
// node_gemm (MFMA): P[n][0:64]   = embed[n] @ W1[0:320]   + cterm
//                   P[n][64:128] = embed[n] @ W1[320:640]
// 256 thr = 4 waves; wave owns 16 rows x 128 cols; K=320 in 10 steps of 32.
// No LDS tiles, no K-loop barriers: A loads global->VGPR (fp32->bf16 cast),
// B loads from Bg (fragment-ordered, L2-resident). 2-deep register dbuf,
// fully unrolled so all buffer indices are compile-time (reg-alloc safe).
// ---------------------------------------------------------------------------
__global__ __launch_bounds__(256) void node_gemm(const float* __restrict__ E,
                                                 const __bf16* __restrict__ Bg,
                                                 const float* __restrict__ W1,
                                                 const float* __restrict__ b1,
                                                 const int* __restrict__ node_id,
                                                 float* __restrict__ P) {
    __shared__ float red[4][64];
    __shared__ float cterm_s[64];
    const int tid = threadIdx.x;

    // ---- per-block cterm: b1 + embed[nid] @ W1[640:960] (fp32) ----
    {
        const int j = tid & 63;
        const int g = tid >> 6;
        const int nid = node_id[0];
        const float* erow = E + (size_t)nid * EMBED_DIM;
        float s = 0.f;
        #pragma unroll 4
        for (int k = g * 80; k < (g + 1) * 80; ++k)
            s = fmaf(erow[k], W1[(size_t)(2 * EMBED_DIM + k) * HID + j], s);
        red[g][j] = s;
    }
    __syncthreads();
    if (tid < 64)
        cterm_s[tid] = b1[tid] + red[0][tid] + red[1][tid] + red[2][tid] + red[3][tid];
    __syncthreads();

    const int wave = tid >> 6;
    const int lane = tid & 63;
    const int r16  = lane & 15;      // A row within tile / C col
    const int kg   = lane >> 4;      // k-group (8 k's each) / C row-group
    const int m0w  = blockIdx.x * 64 + wave * 16;

    int arow_i = m0w + r16;
    if (arow_i > N_NODES - 1) arow_i = N_NODES - 1;   // clamp; OOB rows never stored
    const float*  arow  = E + (size_t)arow_i * EMBED_DIM + kg * 8;
    const __bf16* bbase = Bg + (size_t)lane * 8;

    f32x4 acc[8] = {};

    float4 aA[2][2];
    bf16x8 bB[2][8];

    // prologue: step 0
    aA[0][0] = *(const float4*)(arow + 0);
    aA[0][1] = *(const float4*)(arow + 4);
    #pragma unroll
    for (int f = 0; f < 8; ++f)
        bB[0][f] = *(const bf16x8*)(bbase + (size_t)f * 512);

    #pragma unroll
    for (int s = 0; s < 10; ++s) {
        const int cur = s & 1, nxt = cur ^ 1;
        if (s < 9) {
            const float* an = arow + (s + 1) * 32;
            aA[nxt][0] = *(const float4*)(an + 0);
            aA[nxt][1] = *(const float4*)(an + 4);
            #pragma unroll
            for (int f = 0; f < 8; ++f)
                bB[nxt][f] = *(const bf16x8*)(bbase + (size_t)((s + 1) * 8 + f) * 512);
        }
        bf16x8 av;
        av[0] = (__bf16)aA[cur][0].x; av[1] = (__bf16)aA[cur][0].y;
        av[2] = (__bf16)aA[cur][0].z; av[3] = (__bf16)aA[cur][0].w;
        av[4] = (__bf16)aA[cur][1].x; av[5] = (__bf16)aA[cur][1].y;
        av[6] = (__bf16)aA[cur][1].z; av[7] = (__bf16)aA[cur][1].w;
        #pragma unroll
        for (int f = 0; f < 8; ++f)
            acc[f] = __builtin_amdgcn_mfma_f32_16x16x32_bf16(av, bB[cur][f], acc[f], 0, 0, 0);
    }

    // ---- epilogue: C/D layout col=lane&15, row=(lane>>4)*4+j ----
    #pragma unroll
    for (int f = 0; f < 8; ++f) {
        float ct = (f < 4) ? cterm_s[f * 16 + r16] : 0.f;
        #pragma unroll
        for (int j = 0; j < 4; ++j) {
            int gr = m0w + kg * 4 + j;
            if (gr < N_NODES)
                P[(size_t)gr * 128 + f * 16 + r16] = acc[f][j] + ct;
        }
    }
}

// ---------------------------------------------------------------------------
// edge_kernel: 8 lanes/edge, 2x float4 per operand per lane (256B/row-half).
// h = relu(P[col][0:64] + P[row][64:128]); w = h.W2 + b2   (cterm is in P)
// gate = (log(e) - log1p(-e) + w)/tmp ; out = sigmoid(gate)
// ---------------------------------------------------------------------------
__global__ __launch_bounds__(256) void edge_kernel(const int* __restrict__ eidx,
                                                   const float* __restrict__ eps,
                                                   const float* __restrict__ P,
                                                   const float* __restrict__ W2,
                                                   const float* __restrict__ b2,
                                                   const float* __restrict__ tmp,
                                                   float* __restrict__ out) {
    const int gid = blockIdx.x * blockDim.x + threadIdx.x;
    const int e   = gid >> 3;          // edge id
    const int q   = gid & 7;           // lane within edge group
    if (e >= N_EDGES) return;

    int col = eidx[e];
    int row = eidx[N_EDGES + e];
    col = min(max(col, 0), N_NODES - 1);
    row = min(max(row, 0), N_NODES - 1);

    const float* pc = P + (size_t)col * 128 + q * 8;
    const float* pr = P + (size_t)row * 128 + 64 + q * 8;
    float4 a0 = *(const float4*)(pc + 0);
    float4 a1 = *(const float4*)(pc + 4);
    float4 c0 = *(const float4*)(pr + 0);
    float4 c1 = *(const float4*)(pr + 4);
    float4 w0 = *(const float4*)(W2 + q * 8);
    float4 w1 = *(const float4*)(W2 + q * 8 + 4);

    float s = 0.f;
    s = fmaf(fmaxf(a0.x + c0.x, 0.f), w0.x, s);
    s = fmaf(fmaxf(a0.y + c0.y, 0.f), w0.y, s);
    s = fmaf(fmaxf(a0.z + c0.z, 0.f), w0.z, s);
    s = fmaf(fmaxf(a0.w + c0.w, 0.f), w0.w, s);
    s = fmaf(fmaxf(a1.x + c1.x, 0.f), w1.x, s);
    s = fmaf(fmaxf(a1.y + c1.y, 0.f), w1.y, s);
    s = fmaf(fmaxf(a1.z + c1.z, 0.f), w1.z, s);
    s = fmaf(fmaxf(a1.w + c1.w, 0.f), w1.w, s);

    s += __shfl_xor(s, 1);
    s += __shfl_xor(s, 2);
    s += __shfl_xor(s, 4);

    if (q == 0) {
        float w  = s + b2[0];
        const float bias = 0.0001f;               // SAMPLE_BIAS + 1e-4
        float ee = eps[e] * (1.0f - 2.0f * bias) + bias;
        float gate = (logf(ee) - log1pf(-ee) + w) / tmp[0];
        out[e] = 1.0f / (1.0f + expf(-gate));
    }
}

// ---------------------------------------------------------------------------
extern "C" void kernel_launch(void* const* d_in, const int* in_sizes, int n_in,
                              void* d_out, int out_size, void* d_ws, size_t ws_size,
                              hipStream_t stream) {
    // inputs: x, embed, edge_index, node_id, tmp, eps, W1, b1, W2, b2
    const float* embed = (const float*)d_in[1];
    const int*   eidx  = (const int*)d_in[2];
    const int*   nid   = (const int*)d_in[3];
    const float* tmp   = (const float*)d_in[4];
    const float* eps   = (const float*)d_in[5];
    const float* W1    = (const float*)d_in[6];
    const float* b1    = (const float*)d_in[7];
    const float* W2    = (const float*)d_in[8];
    const float* b2    = (const float*)d_in[9];
    float*       out   = (float*)d_out;

    // workspace: P[50000*128] f32 (25.6 MB), then Bg[5120*8] bf16 (80 KB)
    float*  P  = (float*)d_ws;
    __bf16* Bg = (__bf16*)((char*)d_ws + (size_t)N_NODES * 128 * sizeof(float));

    prep_b<<<20, 256, 0, stream>>>(W1, Bg);

    int gemm_blocks = (N_NODES + 63) / 64;        // 782
    node_gemm<<<gemm_blocks, 256, 0, stream>>>(embed, Bg, W1, b1, nid, P);

    int edge_threads = N_EDGES * 8;               // 3.2M
    edge_kernel<<<(edge_threads + 255) / 256, 256, 0, stream>>>(
        eidx, eps, P, W2, b2, tmp, out);
}

// Round 6
// 162.592 us; speedup vs baseline: 1.3557x; 1.0669x over previous
//
#include <hip/hip_runtime.h>
#include <math.h>

#define N_NODES   50000
#define EMBED_DIM 320
#define N_EDGES   400000
#define HID       64

typedef __bf16 bf16x8 __attribute__((ext_vector_type(8)));
typedef float  f32x4  __attribute__((ext_vector_type(4)));

// ---------------------------------------------------------------------------
// prep_b: repack W1's two 320x64 column-blocks into MFMA B-fragment order (bf16).
//   B[k][c] = W1[k + (c>=64)*320][c&63],  k=0..319, c=0..127
//   Bg[((s*8+f)*64 + l)*8 + j] = (bf16) B[32s + 8*(l>>4) + j][16f + (l&15)]
// ---------------------------------------------------------------------------
__global__ __launch_bounds__(256) void prep_b(const float* __restrict__ W1,
                                              __bf16* __restrict__ Bg) {
    int chunk = blockIdx.x * 256 + threadIdx.x;   // 5120 = 10 steps * 8 frags * 64 lanes
    if (chunk >= 5120) return;
    int l  = chunk & 63;
    int sf = chunk >> 6;
    int f  = sf & 7, s = sf >> 3;
    int c  = f * 16 + (l & 15);
    int k0 = s * 32 + (l >> 4) * 8;
    const float* src = W1 + ((size_t)k0 + (c >= 64 ? EMBED_DIM : 0)) * HID + (c & 63);
    __bf16* dst = Bg + (size_t)chunk * 8;
    #pragma unroll
    for (int j = 0; j < 8; ++j) dst[j] = (__bf16)src[(size_t)j * HID];
}

// ---------------------------------------------------------------------------
// node_gemm (MFMA): P[n][0:64]   = embed[n] @ W1[0:320]   + cterm   (bf16 out)
//                   P[n][64:128] = embed[n] @ W1[320:640]
// Latency fix (R6): ALL 10 K-steps of A are issued up front (20 loads/lane,
// 20 KB/wave in flight -> A stream is BW-bound, not latency-bound). vmcnt is
// in-order, so A-before-B issue order means MFMA step 0 drains the A stream;
// that's fine -- the A stream IS the roofline term. B (L2-resident, fragment-
// ordered) stays 2-deep so per-step waits are one L2 latency, MFMA-covered.
// ---------------------------------------------------------------------------
__global__ __launch_bounds__(256) void node_gemm(const float* __restrict__ E,
                                                 const __bf16* __restrict__ Bg,
                                                 const float* __restrict__ W1,
                                                 const float* __restrict__ b1,
                                                 const int* __restrict__ node_id,
                                                 __bf16* __restrict__ P) {
    __shared__ float red[4][64];
    __shared__ float cterm_s[64];
    const int tid = threadIdx.x;

    // ---- per-block cterm: b1 + embed[nid] @ W1[640:960] (fp32) ----
    {
        const int j = tid & 63;
        const int g = tid >> 6;
        const int nid = node_id[0];
        const float* erow = E + (size_t)nid * EMBED_DIM;
        float s = 0.f;
        #pragma unroll 4
        for (int k = g * 80; k < (g + 1) * 80; ++k)
            s = fmaf(erow[k], W1[(size_t)(2 * EMBED_DIM + k) * HID + j], s);
        red[g][j] = s;
    }
    __syncthreads();
    if (tid < 64)
        cterm_s[tid] = b1[tid] + red[0][tid] + red[1][tid] + red[2][tid] + red[3][tid];
    __syncthreads();

    const int wave = tid >> 6;
    const int lane = tid & 63;
    const int r16  = lane & 15;      // A row within tile / C col
    const int kg   = lane >> 4;      // k-group (8 k's each) / C row-group
    const int m0w  = blockIdx.x * 64 + wave * 16;

    int arow_i = m0w + r16;
    if (arow_i > N_NODES - 1) arow_i = N_NODES - 1;   // clamp; OOB rows never stored
    const float*  arow  = E + (size_t)arow_i * EMBED_DIM + kg * 8;
    const __bf16* bbase = Bg + (size_t)lane * 8;

    f32x4 acc[8] = {};

    // ---- issue the ENTIRE A stream up front (static indices, stays in VGPRs) ----
    float4 aA[10][2];
    #pragma unroll
    for (int s = 0; s < 10; ++s) {
        aA[s][0] = *(const float4*)(arow + s * 32 + 0);
        aA[s][1] = *(const float4*)(arow + s * 32 + 4);
    }

    bf16x8 bB[2][8];
    #pragma unroll
    for (int f = 0; f < 8; ++f)
        bB[0][f] = *(const bf16x8*)(bbase + (size_t)f * 512);

    #pragma unroll
    for (int s = 0; s < 10; ++s) {
        const int cur = s & 1, nxt = cur ^ 1;
        if (s < 9) {
            #pragma unroll
            for (int f = 0; f < 8; ++f)
                bB[nxt][f] = *(const bf16x8*)(bbase + (size_t)((s + 1) * 8 + f) * 512);
        }
        bf16x8 av;
        av[0] = (__bf16)aA[s][0].x; av[1] = (__bf16)aA[s][0].y;
        av[2] = (__bf16)aA[s][0].z; av[3] = (__bf16)aA[s][0].w;
        av[4] = (__bf16)aA[s][1].x; av[5] = (__bf16)aA[s][1].y;
        av[6] = (__bf16)aA[s][1].z; av[7] = (__bf16)aA[s][1].w;
        #pragma unroll
        for (int f = 0; f < 8; ++f)
            acc[f] = __builtin_amdgcn_mfma_f32_16x16x32_bf16(av, bB[cur][f], acc[f], 0, 0, 0);
    }

    // ---- epilogue: C/D layout col=lane&15, row=(lane>>4)*4+j; bf16 store ----
    #pragma unroll
    for (int f = 0; f < 8; ++f) {
        float ct = (f < 4) ? cterm_s[f * 16 + r16] : 0.f;
        #pragma unroll
        for (int j = 0; j < 4; ++j) {
            int gr = m0w + kg * 4 + j;
            if (gr < N_NODES)
                P[(size_t)gr * 128 + f * 16 + r16] = (__bf16)(acc[f][j] + ct);
        }
    }
}

// ---------------------------------------------------------------------------
// edge_kernel: 8 lanes/edge, one bf16x8 (16B) per operand per lane.
// h = relu(P[col][0:64] + P[row][64:128]); w = h.W2 + b2   (cterm is in P)
// gate = (log(e) - log1p(-e) + w)/tmp ; out = sigmoid(gate)
// P is bf16: halves gather traffic; P (12.8 MB) is L2/L3-resident.
// ---------------------------------------------------------------------------
__global__ __launch_bounds__(256) void edge_kernel(const int* __restrict__ eidx,
                                                   const float* __restrict__ eps,
                                                   const __bf16* __restrict__ P,
                                                   const float* __restrict__ W2,
                                                   const float* __restrict__ b2,
                                                   const float* __restrict__ tmp,
                                                   float* __restrict__ out) {
    const int gid = blockIdx.x * blockDim.x + threadIdx.x;
    const int e   = gid >> 3;          // edge id
    const int q   = gid & 7;           // lane within edge group
    if (e >= N_EDGES) return;

    int col = eidx[e];
    int row = eidx[N_EDGES + e];
    col = min(max(col, 0), N_NODES - 1);
    row = min(max(row, 0), N_NODES - 1);

    bf16x8 a = *(const bf16x8*)(P + (size_t)col * 128 + q * 8);
    bf16x8 c = *(const bf16x8*)(P + (size_t)row * 128 + 64 + q * 8);
    float4 w0 = *(const float4*)(W2 + q * 8);
    float4 w1 = *(const float4*)(W2 + q * 8 + 4);

    float s = 0.f;
    s = fmaf(fmaxf((float)a[0] + (float)c[0], 0.f), w0.x, s);
    s = fmaf(fmaxf((float)a[1] + (float)c[1], 0.f), w0.y, s);
    s = fmaf(fmaxf((float)a[2] + (float)c[2], 0.f), w0.z, s);
    s = fmaf(fmaxf((float)a[3] + (float)c[3], 0.f), w0.w, s);
    s = fmaf(fmaxf((float)a[4] + (float)c[4], 0.f), w1.x, s);
    s = fmaf(fmaxf((float)a[5] + (float)c[5], 0.f), w1.y, s);
    s = fmaf(fmaxf((float)a[6] + (float)c[6], 0.f), w1.z, s);
    s = fmaf(fmaxf((float)a[7] + (float)c[7], 0.f), w1.w, s);

    s += __shfl_xor(s, 1);
    s += __shfl_xor(s, 2);
    s += __shfl_xor(s, 4);

    if (q == 0) {
        float w  = s + b2[0];
        const float bias = 0.0001f;               // SAMPLE_BIAS + 1e-4
        float ee = eps[e] * (1.0f - 2.0f * bias) + bias;
        float gate = (logf(ee) - log1pf(-ee) + w) / tmp[0];
        out[e] = 1.0f / (1.0f + expf(-gate));
    }
}

// ---------------------------------------------------------------------------
extern "C" void kernel_launch(void* const* d_in, const int* in_sizes, int n_in,
                              void* d_out, int out_size, void* d_ws, size_t ws_size,
                              hipStream_t stream) {
    // inputs: x, embed, edge_index, node_id, tmp, eps, W1, b1, W2, b2
    const float* embed = (const float*)d_in[1];
    const int*   eidx  = (const int*)d_in[2];
    const int*   nid   = (const int*)d_in[3];
    const float* tmp   = (const float*)d_in[4];
    const float* eps   = (const float*)d_in[5];
    const float* W1    = (const float*)d_in[6];
    const float* b1    = (const float*)d_in[7];
    const float* W2    = (const float*)d_in[8];
    const float* b2    = (const float*)d_in[9];
    float*       out   = (float*)d_out;

    // workspace: P[50000*128] bf16 (12.8 MB, 16B-aligned), then Bg[5120*8] bf16
    __bf16* P  = (__bf16*)d_ws;
    __bf16* Bg = (__bf16*)((char*)d_ws + (size_t)N_NODES * 128 * sizeof(__bf16));

    prep_b<<<20, 256, 0, stream>>>(W1, Bg);

    int gemm_blocks = (N_NODES + 63) / 64;        // 782
    node_gemm<<<gemm_blocks, 256, 0, stream>>>(embed, Bg, W1, b1, nid, P);

    int edge_threads = N_EDGES * 8;               // 3.2M
    edge_kernel<<<(edge_threads + 255) / 256, 256, 0, stream>>>(
        eidx, eps, P, W2, b2, tmp, out);
}

// Round 7
// 148.303 us; speedup vs baseline: 1.4863x; 1.0964x over previous
//
#include <hip/hip_runtime.h>
#include <math.h>
#include <stdint.h>

#define N_NODES   50000
#define EMBED_DIM 320
#define N_EDGES   400000
#define HID       64

typedef __bf16 bf16x8 __attribute__((ext_vector_type(8)));
typedef float  f32x4  __attribute__((ext_vector_type(4)));

// direct-to-LDS DMA, 16B per lane. No VGPR destination -> compiler cannot
// sink it; issues exactly where written (the R6 register-prefetch was
// silently sunk: VGPR_Count=64 < the 80 the prefetch needed).
__device__ __forceinline__ void async_copy16(void* lds_dst, const void* g_src) {
    __builtin_amdgcn_global_load_lds(
        (const __attribute__((address_space(1))) uint32_t*)g_src,
        (__attribute__((address_space(3))) uint32_t*)lds_dst,
        16, 0, 0);
}

// ---------------------------------------------------------------------------
// prep_b: blocks 0..19 repack W1 -> Bg (MFMA B-fragment order, bf16);
//         block 20 computes cterm = b1 + embed[nid] @ W1[640:960] (fp32).
// cterm is block-invariant -- computing it inside every node_gemm block (R3-R6)
// was pure serial overhead on the streaming path.
//   Bg[((s*8+f)*64 + l)*8 + j] = (bf16) B[32s + 8*(l>>4) + j][16f + (l&15)]
//   where B[k][c] = W1[k + (c>=64)*320][c&63]
// ---------------------------------------------------------------------------
__global__ __launch_bounds__(256) void prep_b(const float* __restrict__ W1,
                                              const float* __restrict__ b1,
                                              const int* __restrict__ node_id,
                                              const float* __restrict__ E,
                                              __bf16* __restrict__ Bg,
                                              float* __restrict__ cterm_g) {
    if (blockIdx.x < 20) {
        int chunk = blockIdx.x * 256 + threadIdx.x;   // < 5120
        int l  = chunk & 63;
        int sf = chunk >> 6;
        int f  = sf & 7, s = sf >> 3;
        int c  = f * 16 + (l & 15);
        int k0 = s * 32 + (l >> 4) * 8;
        const float* src = W1 + ((size_t)k0 + (c >= 64 ? EMBED_DIM : 0)) * HID + (c & 63);
        __bf16* dst = Bg + (size_t)chunk * 8;
        #pragma unroll
        for (int j = 0; j < 8; ++j) dst[j] = (__bf16)src[(size_t)j * HID];
    } else {
        __shared__ float red[4][64];
        const int tid = threadIdx.x;
        const int j = tid & 63;
        const int g = tid >> 6;
        const int nid = node_id[0];
        const float* erow = E + (size_t)nid * EMBED_DIM;
        float s = 0.f;
        #pragma unroll 4
        for (int k = g * 80; k < (g + 1) * 80; ++k)
            s = fmaf(erow[k], W1[(size_t)(2 * EMBED_DIM + k) * HID + j], s);
        red[g][j] = s;
        __syncthreads();
        if (tid < 64)
            cterm_g[tid] = b1[tid] + red[0][tid] + red[1][tid] + red[2][tid] + red[3][tid];
    }
}

// ---------------------------------------------------------------------------
// node_gemm (MFMA): P[n][0:64]   = embed[n] @ W1[0:320]   + cterm   (bf16 out)
//                   P[n][64:128] = embed[n] @ W1[320:640]
// Block = 256 thr (4 waves), 64 rows. The whole 64x320 fp32 A-tile (80 KB) is
// DMA'd to LDS up front (20 global_load_lds x 16B per wave, fire-and-forget)
// -> 2 blocks/CU resident -> ~160 KB in flight per CU: A stream is BW-bound.
// LDS swizzle (rule #21): DMA dest linear, global SOURCE chunk pre-XORed with
// (row&7), ds_read applies the same XOR -> row-stride-1280B reads go from
// 16-lane same-bank to conflict-free.
// B fragments: 4-deep register ring from fragment-ordered Bg (L2-resident),
// ~3 steps of L2-latency cover.
// ---------------------------------------------------------------------------
__global__ __launch_bounds__(256) void node_gemm(const float* __restrict__ E,
                                                 const __bf16* __restrict__ Bg,
                                                 const float* __restrict__ cterm_g,
                                                 __bf16* __restrict__ P) {
    __shared__ float sA[64 * EMBED_DIM];   // 80 KB exactly

    const int tid  = threadIdx.x;
    const int wave = tid >> 6;
    const int lane = tid & 63;
    const int r16  = lane & 15;    // A row within wave tile / C col
    const int kg   = lane >> 4;    // k-group / C row-group
    const int m0   = blockIdx.x * 64;

    // ---- 1) issue the whole A tile as direct-to-LDS DMA ----
    #pragma unroll
    for (int it = 0; it < 20; ++it) {
        int g   = it * 256 + tid;          // chunk id, 0..5119 (16B chunks)
        int r   = g / 80;                  // tile row 0..63
        int cw  = g - r * 80;              // chunk within row
        int scw = cw ^ (r & 7);            // inverse-swizzled SOURCE chunk
        int gr  = m0 + r;
        if (gr > N_NODES - 1) gr = N_NODES - 1;   // dup row; OOB rows never stored
        async_copy16((char*)sA + (size_t)g * 16,
                     E + (size_t)gr * EMBED_DIM + scw * 4);
    }

    // ---- 2) per-lane cterm + B prologue (issued behind the DMA stream) ----
    float ct[4];
    #pragma unroll
    for (int f = 0; f < 4; ++f) ct[f] = cterm_g[f * 16 + r16];

    const __bf16* bbase = Bg + (size_t)lane * 8;
    bf16x8 bB[4][8];
    #pragma unroll
    for (int s = 0; s < 4; ++s)
        #pragma unroll
        for (int f = 0; f < 8; ++f)
            bB[s][f] = *(const bf16x8*)(bbase + (size_t)(s * 8 + f) * 512);

    f32x4 acc[8] = {};

    asm volatile("s_waitcnt vmcnt(0)" ::: "memory");
    __syncthreads();

    // ---- 3) MFMA loop: A from LDS (swizzled), B 4-deep ring ----
    const int rt      = wave * 16 + r16;        // row within 64-row tile
    const int rowbase = rt * EMBED_DIM;         // rt&7 == r16&7 (wave*16 % 8 == 0)
    #pragma unroll
    for (int s = 0; s < 10; ++s) {
        int cb = s * 8 + kg * 2;
        int c0 = cb ^ (r16 & 7);
        int c1 = (cb + 1) ^ (r16 & 7);
        f32x4 lo = *(const f32x4*)&sA[rowbase + c0 * 4];
        f32x4 hi = *(const f32x4*)&sA[rowbase + c1 * 4];
        bf16x8 av;
        av[0] = (__bf16)lo[0]; av[1] = (__bf16)lo[1];
        av[2] = (__bf16)lo[2]; av[3] = (__bf16)lo[3];
        av[4] = (__bf16)hi[0]; av[5] = (__bf16)hi[1];
        av[6] = (__bf16)hi[2]; av[7] = (__bf16)hi[3];
        #pragma unroll
        for (int f = 0; f < 8; ++f)
            acc[f] = __builtin_amdgcn_mfma_f32_16x16x32_bf16(av, bB[s & 3][f], acc[f], 0, 0, 0);
        if (s < 6) {   // refill the slot just consumed with step s+4
            #pragma unroll
            for (int f = 0; f < 8; ++f)
                bB[s & 3][f] = *(const bf16x8*)(bbase + (size_t)((s + 4) * 8 + f) * 512);
        }
    }

    // ---- 4) epilogue: C/D layout col=lane&15, row=(lane>>4)*4+j; bf16 store ----
    const int m0w = m0 + wave * 16;
    #pragma unroll
    for (int f = 0; f < 8; ++f) {
        float c = (f < 4) ? ct[f] : 0.f;
        #pragma unroll
        for (int j = 0; j < 4; ++j) {
            int gr = m0w + kg * 4 + j;
            if (gr < N_NODES)
                P[(size_t)gr * 128 + f * 16 + r16] = (__bf16)(acc[f][j] + c);
        }
    }
}

// ---------------------------------------------------------------------------
// edge_kernel: 8 lanes/edge, one bf16x8 (16B) per operand per lane.
// h = relu(P[col][0:64] + P[row][64:128]); w = h.W2 + b2   (cterm is in P)
// gate = (log(e) - log1p(-e) + w)/tmp ; out = sigmoid(gate)
// ---------------------------------------------------------------------------
__global__ __launch_bounds__(256) void edge_kernel(const int* __restrict__ eidx,
                                                   const float* __restrict__ eps,
                                                   const __bf16* __restrict__ P,
                                                   const float* __restrict__ W2,
                                                   const float* __restrict__ b2,
                                                   const float* __restrict__ tmp,
                                                   float* __restrict__ out) {
    const int gid = blockIdx.x * blockDim.x + threadIdx.x;
    const int e   = gid >> 3;          // edge id
    const int q   = gid & 7;           // lane within edge group
    if (e >= N_EDGES) return;

    int col = eidx[e];
    int row = eidx[N_EDGES + e];
    col = min(max(col, 0), N_NODES - 1);
    row = min(max(row, 0), N_NODES - 1);

    bf16x8 a = *(const bf16x8*)(P + (size_t)col * 128 + q * 8);
    bf16x8 c = *(const bf16x8*)(P + (size_t)row * 128 + 64 + q * 8);
    float4 w0 = *(const float4*)(W2 + q * 8);
    float4 w1 = *(const float4*)(W2 + q * 8 + 4);

    float s = 0.f;
    s = fmaf(fmaxf((float)a[0] + (float)c[0], 0.f), w0.x, s);
    s = fmaf(fmaxf((float)a[1] + (float)c[1], 0.f), w0.y, s);
    s = fmaf(fmaxf((float)a[2] + (float)c[2], 0.f), w0.z, s);
    s = fmaf(fmaxf((float)a[3] + (float)c[3], 0.f), w0.w, s);
    s = fmaf(fmaxf((float)a[4] + (float)c[4], 0.f), w1.x, s);
    s = fmaf(fmaxf((float)a[5] + (float)c[5], 0.f), w1.y, s);
    s = fmaf(fmaxf((float)a[6] + (float)c[6], 0.f), w1.z, s);
    s = fmaf(fmaxf((float)a[7] + (float)c[7], 0.f), w1.w, s);

    s += __shfl_xor(s, 1);
    s += __shfl_xor(s, 2);
    s += __shfl_xor(s, 4);

    if (q == 0) {
        float w  = s + b2[0];
        const float bias = 0.0001f;               // SAMPLE_BIAS + 1e-4
        float ee = eps[e] * (1.0f - 2.0f * bias) + bias;
        float gate = (logf(ee) - log1pf(-ee) + w) / tmp[0];
        out[e] = 1.0f / (1.0f + expf(-gate));
    }
}

// ---------------------------------------------------------------------------
extern "C" void kernel_launch(void* const* d_in, const int* in_sizes, int n_in,
                              void* d_out, int out_size, void* d_ws, size_t ws_size,
                              hipStream_t stream) {
    // inputs: x, embed, edge_index, node_id, tmp, eps, W1, b1, W2, b2
    const float* embed = (const float*)d_in[1];
    const int*   eidx  = (const int*)d_in[2];
    const int*   nid   = (const int*)d_in[3];
    const float* tmp   = (const float*)d_in[4];
    const float* eps   = (const float*)d_in[5];
    const float* W1    = (const float*)d_in[6];
    const float* b1    = (const float*)d_in[7];
    const float* W2    = (const float*)d_in[8];
    const float* b2    = (const float*)d_in[9];
    float*       out   = (float*)d_out;

    // workspace: P[50000*128] bf16 (12.8 MB) | Bg[5120*8] bf16 (80 KB) | cterm[64] f32
    __bf16* P       = (__bf16*)d_ws;
    __bf16* Bg      = (__bf16*)((char*)d_ws + (size_t)N_NODES * 128 * sizeof(__bf16));
    float*  cterm_g = (float*)((char*)Bg + (size_t)5120 * 8 * sizeof(__bf16));

    prep_b<<<21, 256, 0, stream>>>(W1, b1, nid, embed, Bg, cterm_g);

    int gemm_blocks = (N_NODES + 63) / 64;        // 782
    node_gemm<<<gemm_blocks, 256, 0, stream>>>(embed, Bg, cterm_g, P);

    int edge_threads = N_EDGES * 8;               // 3.2M
    edge_kernel<<<(edge_threads + 255) / 256, 256, 0, stream>>>(
        eidx, eps, P, W2, b2, tmp, out);
}

// Round 8
// 145.845 us; speedup vs baseline: 1.5114x; 1.0169x over previous
//
#include <hip/hip_runtime.h>
#include <math.h>
#include <stdint.h>

#define N_NODES   50000
#define EMBED_DIM 320
#define N_EDGES   400000
#define HID       64

typedef __bf16 bf16x8 __attribute__((ext_vector_type(8)));
typedef float  f32x4  __attribute__((ext_vector_type(4)));

// direct-to-LDS DMA, 16B per lane. No VGPR destination -> compiler cannot
// sink it (R6 lesson: a register prefetch was silently sunk to hold occupancy).
__device__ __forceinline__ void async_copy16(void* lds_dst, const void* g_src) {
    __builtin_amdgcn_global_load_lds(
        (const __attribute__((address_space(1))) uint32_t*)g_src,
        (__attribute__((address_space(3))) uint32_t*)lds_dst,
        16, 0, 0);
}

// ---------------------------------------------------------------------------
// prep_b: blocks 0..19 repack W1 -> Bg (MFMA B-fragment order, bf16);
//         block 20 computes cterm = b1 + embed[nid] @ W1[640:960] (fp32).
//   Bg[((s*8+f)*64 + l)*8 + j] = (bf16) B[32s + 8*(l>>4) + j][16f + (l&15)]
//   where B[k][c] = W1[k + (c>=64)*320][c&63]
// ---------------------------------------------------------------------------
__global__ __launch_bounds__(256) void prep_b(const float* __restrict__ W1,
                                              const float* __restrict__ b1,
                                              const int* __restrict__ node_id,
                                              const float* __restrict__ E,
                                              __bf16* __restrict__ Bg,
                                              float* __restrict__ cterm_g) {
    if (blockIdx.x < 20) {
        int chunk = blockIdx.x * 256 + threadIdx.x;   // < 5120
        int l  = chunk & 63;
        int sf = chunk >> 6;
        int f  = sf & 7, s = sf >> 3;
        int c  = f * 16 + (l & 15);
        int k0 = s * 32 + (l >> 4) * 8;
        const float* src = W1 + ((size_t)k0 + (c >= 64 ? EMBED_DIM : 0)) * HID + (c & 63);
        __bf16* dst = Bg + (size_t)chunk * 8;
        #pragma unroll
        for (int j = 0; j < 8; ++j) dst[j] = (__bf16)src[(size_t)j * HID];
    } else {
        __shared__ float red[4][64];
        const int tid = threadIdx.x;
        const int j = tid & 63;
        const int g = tid >> 6;
        const int nid = node_id[0];
        const float* erow = E + (size_t)nid * EMBED_DIM;
        float s = 0.f;
        #pragma unroll 4
        for (int k = g * 80; k < (g + 1) * 80; ++k)
            s = fmaf(erow[k], W1[(size_t)(2 * EMBED_DIM + k) * HID + j], s);
        red[g][j] = s;
        __syncthreads();
        if (tid < 64)
            cterm_g[tid] = b1[tid] + red[0][tid] + red[1][tid] + red[2][tid] + red[3][tid];
    }
}

// ---------------------------------------------------------------------------
// node_gemm (MFMA): P[n][0:64]   = embed[n] @ W1[0:320]   + cterm   (bf16 out)
//                   P[n][64:128] = embed[n] @ W1[320:640]
// R8: 32-row tiles (40 KB LDS) -> 4 blocks/CU resident (4x40960 = 160 KiB
// exactly), 16 waves/CU. Same sync template as the working R7 kernel
// (DMA-all -> vmcnt(0) -> barrier -> compute); TLP across 4 staggered blocks
// now covers each block's drain/compute/retire gaps. 1563-block grid kills
// the 25% tail round of the 782-block version.
// Wave layout: wave = (rowgrp = w&1)*16 rows  x  (colgrp = w>>1)*64 cols.
// LDS swizzle (rule #21): DMA dest linear, global SOURCE chunk pre-XORed with
// (row&7), ds_read applies the same XOR.
// ---------------------------------------------------------------------------
__global__ __launch_bounds__(256, 4) void node_gemm(const float* __restrict__ E,
                                                    const __bf16* __restrict__ Bg,
                                                    const float* __restrict__ cterm_g,
                                                    __bf16* __restrict__ P) {
    __shared__ float sA[32 * EMBED_DIM];   // 40 KB exactly

    const int tid  = threadIdx.x;
    const int wave = tid >> 6;
    const int lane = tid & 63;
    const int r16  = lane & 15;    // A row within 16-row group / C col
    const int kg   = lane >> 4;    // k-group / C row-group
    const int rowg = wave & 1;     // which 16-row half of the tile
    const int colg = wave >> 1;    // which 64-col half of the output
    const int m0   = blockIdx.x * 32;

    // ---- 1) DMA the whole 32x320 fp32 A tile to LDS (10 chunks/thread) ----
    #pragma unroll
    for (int it = 0; it < 10; ++it) {
        int g   = it * 256 + tid;          // chunk id, 0..2559 (16B chunks)
        int r   = g / 80;                  // tile row 0..31
        int cw  = g - r * 80;              // chunk within row
        int scw = cw ^ (r & 7);            // inverse-swizzled SOURCE chunk
        int gr  = m0 + r;
        if (gr > N_NODES - 1) gr = N_NODES - 1;   // dup row; OOB rows never stored
        async_copy16((char*)sA + (size_t)g * 16,
                     E + (size_t)gr * EMBED_DIM + scw * 4);
    }

    // ---- 2) per-lane cterm (col-half only) + B prologue ----
    float ct[4];
    #pragma unroll
    for (int fi = 0; fi < 4; ++fi)
        ct[fi] = (colg == 0) ? cterm_g[fi * 16 + r16] : 0.f;

    // frag (s, f=colg*4+fi) lives at Bg + ((s*8 + colg*4 + fi)*64 + lane)*8
    const __bf16* bbase = Bg + (size_t)colg * 2048 + (size_t)lane * 8;
    bf16x8 bB[4][4];
    #pragma unroll
    for (int s = 0; s < 4; ++s)
        #pragma unroll
        for (int fi = 0; fi < 4; ++fi)
            bB[s][fi] = *(const bf16x8*)(bbase + (size_t)(s * 8 + fi) * 512);

    f32x4 acc[4] = {};

    asm volatile("s_waitcnt vmcnt(0)" ::: "memory");
    __syncthreads();

    // ---- 3) MFMA loop: A from LDS (swizzled), B 4-deep register ring ----
    const int rowbase = (rowg * 16 + r16) * EMBED_DIM;   // (row&7)==r16&7
    #pragma unroll
    for (int s = 0; s < 10; ++s) {
        int cb = s * 8 + kg * 2;
        int c0 = cb ^ (r16 & 7);
        int c1 = (cb + 1) ^ (r16 & 7);
        f32x4 lo = *(const f32x4*)&sA[rowbase + c0 * 4];
        f32x4 hi = *(const f32x4*)&sA[rowbase + c1 * 4];
        bf16x8 av;
        av[0] = (__bf16)lo[0]; av[1] = (__bf16)lo[1];
        av[2] = (__bf16)lo[2]; av[3] = (__bf16)lo[3];
        av[4] = (__bf16)hi[0]; av[5] = (__bf16)hi[1];
        av[6] = (__bf16)hi[2]; av[7] = (__bf16)hi[3];
        #pragma unroll
        for (int fi = 0; fi < 4; ++fi)
            acc[fi] = __builtin_amdgcn_mfma_f32_16x16x32_bf16(av, bB[s & 3][fi], acc[fi], 0, 0, 0);
        if (s < 6) {   // refill consumed slot with step s+4
            #pragma unroll
            for (int fi = 0; fi < 4; ++fi)
                bB[s & 3][fi] = *(const bf16x8*)(bbase + (size_t)((s + 4) * 8 + fi) * 512);
        }
    }

    // ---- 4) epilogue: C/D layout col=lane&15, row=(lane>>4)*4+j; bf16 store ----
    const int m0w = m0 + rowg * 16;
    #pragma unroll
    for (int fi = 0; fi < 4; ++fi) {
        #pragma unroll
        for (int j = 0; j < 4; ++j) {
            int gr = m0w + kg * 4 + j;
            if (gr < N_NODES)
                P[(size_t)gr * 128 + colg * 64 + fi * 16 + r16] = (__bf16)(acc[fi][j] + ct[fi]);
        }
    }
}

// ---------------------------------------------------------------------------
// edge_kernel: 8 lanes/edge, one bf16x8 (16B) per operand per lane.
// h = relu(P[col][0:64] + P[row][64:128]); w = h.W2 + b2   (cterm is in P)
// gate = (log(e) - log1p(-e) + w)/tmp ; out = sigmoid(gate)
// ---------------------------------------------------------------------------
__global__ __launch_bounds__(256) void edge_kernel(const int* __restrict__ eidx,
                                                   const float* __restrict__ eps,
                                                   const __bf16* __restrict__ P,
                                                   const float* __restrict__ W2,
                                                   const float* __restrict__ b2,
                                                   const float* __restrict__ tmp,
                                                   float* __restrict__ out) {
    const int gid = blockIdx.x * blockDim.x + threadIdx.x;
    const int e   = gid >> 3;          // edge id
    const int q   = gid & 7;           // lane within edge group
    if (e >= N_EDGES) return;

    int col = eidx[e];
    int row = eidx[N_EDGES + e];
    col = min(max(col, 0), N_NODES - 1);
    row = min(max(row, 0), N_NODES - 1);

    bf16x8 a = *(const bf16x8*)(P + (size_t)col * 128 + q * 8);
    bf16x8 c = *(const bf16x8*)(P + (size_t)row * 128 + 64 + q * 8);
    float4 w0 = *(const float4*)(W2 + q * 8);
    float4 w1 = *(const float4*)(W2 + q * 8 + 4);

    float s = 0.f;
    s = fmaf(fmaxf((float)a[0] + (float)c[0], 0.f), w0.x, s);
    s = fmaf(fmaxf((float)a[1] + (float)c[1], 0.f), w0.y, s);
    s = fmaf(fmaxf((float)a[2] + (float)c[2], 0.f), w0.z, s);
    s = fmaf(fmaxf((float)a[3] + (float)c[3], 0.f), w0.w, s);
    s = fmaf(fmaxf((float)a[4] + (float)c[4], 0.f), w1.x, s);
    s = fmaf(fmaxf((float)a[5] + (float)c[5], 0.f), w1.y, s);
    s = fmaf(fmaxf((float)a[6] + (float)c[6], 0.f), w1.z, s);
    s = fmaf(fmaxf((float)a[7] + (float)c[7], 0.f), w1.w, s);

    s += __shfl_xor(s, 1);
    s += __shfl_xor(s, 2);
    s += __shfl_xor(s, 4);

    if (q == 0) {
        float w  = s + b2[0];
        const float bias = 0.0001f;               // SAMPLE_BIAS + 1e-4
        float ee = eps[e] * (1.0f - 2.0f * bias) + bias;
        float gate = (logf(ee) - log1pf(-ee) + w) / tmp[0];
        out[e] = 1.0f / (1.0f + expf(-gate));
    }
}

// ---------------------------------------------------------------------------
extern "C" void kernel_launch(void* const* d_in, const int* in_sizes, int n_in,
                              void* d_out, int out_size, void* d_ws, size_t ws_size,
                              hipStream_t stream) {
    // inputs: x, embed, edge_index, node_id, tmp, eps, W1, b1, W2, b2
    const float* embed = (const float*)d_in[1];
    const int*   eidx  = (const int*)d_in[2];
    const int*   nid   = (const int*)d_in[3];
    const float* tmp   = (const float*)d_in[4];
    const float* eps   = (const float*)d_in[5];
    const float* W1    = (const float*)d_in[6];
    const float* b1    = (const float*)d_in[7];
    const float* W2    = (const float*)d_in[8];
    const float* b2    = (const float*)d_in[9];
    float*       out   = (float*)d_out;

    // workspace: P[50000*128] bf16 (12.8 MB) | Bg[5120*8] bf16 (80 KB) | cterm[64] f32
    __bf16* P       = (__bf16*)d_ws;
    __bf16* Bg      = (__bf16*)((char*)d_ws + (size_t)N_NODES * 128 * sizeof(__bf16));
    float*  cterm_g = (float*)((char*)Bg + (size_t)5120 * 8 * sizeof(__bf16));

    prep_b<<<21, 256, 0, stream>>>(W1, b1, nid, embed, Bg, cterm_g);

    int gemm_blocks = (N_NODES + 31) / 32;        // 1563
    node_gemm<<<gemm_blocks, 256, 0, stream>>>(embed, Bg, cterm_g, P);

    int edge_threads = N_EDGES * 8;               // 3.2M
    edge_kernel<<<(edge_threads + 255) / 256, 256, 0, stream>>>(
        eidx, eps, P, W2, b2, tmp, out);
}